// Round 4
// baseline (606.205 us; speedup 1.0000x reference)
//
#include <hip/hip_runtime.h>
#include <hip/hip_fp16.h>
#include <cstdint>

#define NNODES 50000
#define RANGES 4
#define RSPAN 12500  // NNODES / RANGES

typedef unsigned int nvec4 __attribute__((ext_vector_type(4)));  // native vec for nontemporal builtins

__device__ inline void wave_lds_fence() {
  asm volatile("s_waitcnt lgkmcnt(0)" ::: "memory");
  __builtin_amdgcn_wave_barrier();
}

// ---------------- segmented CSR build: segment = dst*RANGES + src/RSPAN ----------------
__global__ void hist_kernel(const int* __restrict__ ei, int E, int Nn, int* __restrict__ cnt) {
  int i = blockIdx.x * blockDim.x + threadIdx.x;
  int ET = E + Nn;
  if (i >= ET) return;
  int s, d;
  if (i < E) { s = ei[i]; d = ei[E + i]; }
  else       { s = i - E; d = i - E; }
  atomicAdd(&cnt[d * RANGES + s / RSPAN], 1);
}

__global__ void scan1_kernel(const int* __restrict__ in, int n, int* __restrict__ incl,
                             int* __restrict__ bsum) {
  __shared__ int sd[256];
  int g = blockIdx.x * 256 + threadIdx.x;
  int v = (g < n) ? in[g] : 0;
  sd[threadIdx.x] = v;
  __syncthreads();
  for (int off = 1; off < 256; off <<= 1) {
    int t = (threadIdx.x >= off) ? sd[threadIdx.x - off] : 0;
    __syncthreads();
    sd[threadIdx.x] += t;
    __syncthreads();
  }
  if (g < n) incl[g] = sd[threadIdx.x];
  if (threadIdx.x == 255) bsum[blockIdx.x] = sd[255];
}

// segptr[g+1] = incl0[g] + global-exclusive-prefix(block b0) using two scan levels
__global__ void scan3seg_kernel(const int* __restrict__ incl0, const int* __restrict__ incl1,
                                const int* __restrict__ incl2, int n, int* __restrict__ segptr) {
  int g = blockIdx.x * 256 + threadIdx.x;
  if (g == 0) segptr[0] = 0;
  if (g < n) {
    int b0 = g >> 8;
    int off = 0;
    if (b0 > 0) {
      int i = b0 - 1;
      off = incl1[i];
      int j = i >> 8;
      if (j > 0) off += incl2[j - 1];
    }
    segptr[g + 1] = incl0[g] + off;
  }
}

__global__ void scatter_kernel(const int* __restrict__ ei, int E, int Nn,
                               const int* __restrict__ segptr, int* __restrict__ cnt2,
                               int* __restrict__ esorted) {
  int i = blockIdx.x * blockDim.x + threadIdx.x;
  int ET = E + Nn;
  if (i >= ET) return;
  int s, d;
  if (i < E) { s = ei[i]; d = ei[E + i]; }
  else       { s = i - E; d = i - E; }
  int seg = d * RANGES + s / RSPAN;
  int pos = segptr[seg] + atomicAdd(&cnt2[seg], 1);
  esorted[pos] = s;
}

// ---------------- GEMM: Hout[N,HCP](fp16, row stride HCP) = X[N,FIN](fp32) @ W[FIN,HC] ------
template <int FIN, int HC, int HCP, int BLOCK>
__global__ __launch_bounds__(BLOCK) void gemm_kernel(const float* __restrict__ X,
                                                     const float* __restrict__ W,
                                                     __half* __restrict__ Hout) {
  constexpr int NT = 16;
  constexpr int TM = 4, TN = 4;
  constexpr int CG = HC / TN;
  __shared__ __align__(16) float xs[FIN * NT];  // [k][node]
  const int n0 = blockIdx.x * NT;
  for (int i = threadIdx.x * 4; i < NT * FIN; i += BLOCK * 4) {
    float4 v = *(const float4*)(X + (size_t)n0 * FIN + i);
    int node = i / FIN, k = i % FIN;
    xs[(k + 0) * NT + node] = v.x;
    xs[(k + 1) * NT + node] = v.y;
    xs[(k + 2) * NT + node] = v.z;
    xs[(k + 3) * NT + node] = v.w;
  }
  __syncthreads();
  const int cg = threadIdx.x % CG;
  const int ng = threadIdx.x / CG;
  if (ng >= NT / TM) return;
  const int c0 = cg * TN;
  const int i0 = ng * TM;
  float acc[TM][TN];
#pragma unroll
  for (int i = 0; i < TM; ++i)
#pragma unroll
    for (int j = 0; j < TN; ++j) acc[i][j] = 0.f;
#pragma unroll 4
  for (int k = 0; k < FIN; ++k) {
    const float4 wv = *(const float4*)(W + (size_t)k * HC + c0);
    const float4 xv = *(const float4*)(xs + k * NT + i0);
    acc[0][0] += xv.x * wv.x; acc[0][1] += xv.x * wv.y; acc[0][2] += xv.x * wv.z; acc[0][3] += xv.x * wv.w;
    acc[1][0] += xv.y * wv.x; acc[1][1] += xv.y * wv.y; acc[1][2] += xv.y * wv.z; acc[1][3] += xv.y * wv.w;
    acc[2][0] += xv.z * wv.x; acc[2][1] += xv.z * wv.y; acc[2][2] += xv.z * wv.z; acc[2][3] += xv.z * wv.w;
    acc[3][0] += xv.w * wv.x; acc[3][1] += xv.w * wv.y; acc[3][2] += xv.w * wv.z; acc[3][3] += xv.w * wv.w;
  }
#pragma unroll
  for (int i = 0; i < TM; ++i) {
    union { __half2 h2[2]; uint2 u; } pk;
    pk.h2[0] = __floats2half2_rn(acc[i][0], acc[i][1]);
    pk.h2[1] = __floats2half2_rn(acc[i][2], acc[i][3]);
    *(uint2*)(Hout + (size_t)(n0 + i0 + i) * HCP + c0) = pk.u;
  }
}

// ---------------- attention logits ----------------
template <int H, int C, int HCP>
__global__ void alpha_kernel(const __half* __restrict__ Hbuf, const float* __restrict__ a_s,
                             const float* __restrict__ a_d, float* __restrict__ als8,
                             float* __restrict__ ald8, int n_nodes) {
  int i = blockIdx.x * blockDim.x + threadIdx.x;
  if (i >= n_nodes * H) return;
  int n = i / H, h = i % H;
  const __half2* hp = (const __half2*)(Hbuf + (size_t)n * HCP + (size_t)h * C);
  float s1 = 0.f, s2 = 0.f;
#pragma unroll
  for (int c = 0; c < C / 2; ++c) {
    float2 f = __half22float2(hp[c]);
    s1 += f.x * a_s[h * C + 2 * c] + f.y * a_s[h * C + 2 * c + 1];
    s2 += f.x * a_d[h * C + 2 * c] + f.y * a_d[h * C + 2 * c + 1];
  }
  als8[n * 8 + h] = s1;
  ald8[n * 8 + h] = s2;
}

// ======================= full-row segment softmax + aggregate (plain path) ==================
// Used for layer 3 (range footprint too big for L2) and as ws_size fallback.
// Row = 4 contiguous segments [segptr[n*4], segptr[n*4+4]).
template <int H, int C, int HCP, int RELU>
__global__ __launch_bounds__(256) void agg_kernel(const __half* __restrict__ Hbuf,
                                                  const float* __restrict__ als8,
                                                  const float* __restrict__ ald8,
                                                  const int* __restrict__ segptr,
                                                  const int* __restrict__ esrc,
                                                  const float* __restrict__ bias,
                                                  float* __restrict__ Out, int n_nodes) {
  constexpr int HC = H * C;
  constexpr int NCHUNK = HC / 8;
  constexpr int GROUPS = (NCHUNK <= 16) ? 4 : 2;
  constexpr int LPG = 64 / GROUPS;
  constexpr int UN = 3;
  constexpr int TPAD = 72;
  const int wave = threadIdx.x >> 6;
  const int lane = threadIdx.x & 63;
  const int grp = lane / LPG;
  const int lg = lane % LPG;
  const int n = blockIdx.x * 4 + wave;
  __shared__ float s_w[4][TPAD * H];
  __shared__ int s_src[4][TPAD];
  if (n >= n_nodes) return;

  if (lane < TPAD - 64) s_src[wave][64 + lane] = 0;
  for (int z = lane; z < (TPAD - 64) * H; z += 64) s_w[wave][64 * H + z] = 0.f;

  const int e0 = segptr[n * RANGES];
  const int e1 = segptr[n * RANGES + RANGES];

  float aldn[H];
#pragma unroll
  for (int h = 0; h < H; ++h) aldn[h] = ald8[n * 8 + h];

  const int head = min((lg * 8) / C, H - 1);
  const bool act = lg < NCHUNK;

  float acc[8];
  float lsum = 0.f;
#pragma unroll
  for (int j = 0; j < 8; ++j) acc[j] = 0.f;

  for (int base = e0; base < e1; base += 64) {
    const int cnt = (e1 - base < 64) ? (e1 - base) : 64;
    int sreg = 0;
    if (lane < cnt) sreg = esrc[base + lane];
    s_src[wave][lane] = sreg;
    if (lane < cnt) {
      const float4 qa = *(const float4*)(als8 + (size_t)sreg * 8);
      const float4 qb = *(const float4*)(als8 + (size_t)sreg * 8 + 4);
      const float q[8] = {qa.x, qa.y, qa.z, qa.w, qb.x, qb.y, qb.z, qb.w};
#pragma unroll
      for (int h = 0; h < H; ++h) {
        float v = q[h] + aldn[h];
        v = v > 0.f ? v : 0.2f * v;
        s_w[wave][lane * H + h] = __expf(v);
      }
    } else {
#pragma unroll
      for (int h = 0; h < H; ++h) s_w[wave][lane * H + h] = 0.f;
    }
    wave_lds_fence();
    const int nit = (cnt + GROUPS - 1) / GROUPS;
    for (int i = 0; i < nit; i += UN) {
      int tt[UN], si[UN];
      uint4 v[UN];
      float w[UN];
#pragma unroll
      for (int k = 0; k < UN; ++k) tt[k] = (i + k) * GROUPS + grp;
#pragma unroll
      for (int k = 0; k < UN; ++k) si[k] = s_src[wave][tt[k]];
#pragma unroll
      for (int k = 0; k < UN; ++k)
        if (act) v[k] = *(const uint4*)(Hbuf + (size_t)si[k] * HCP + lg * 8);
#pragma unroll
      for (int k = 0; k < UN; ++k) w[k] = s_w[wave][tt[k] * H + head];
#pragma unroll
      for (int k = 0; k < UN; ++k)
        if (act) {
          const __half2* hp = (const __half2*)&v[k];
          float2 f0 = __half22float2(hp[0]);
          float2 f1 = __half22float2(hp[1]);
          float2 f2 = __half22float2(hp[2]);
          float2 f3 = __half22float2(hp[3]);
          lsum += w[k];
          acc[0] += w[k] * f0.x; acc[1] += w[k] * f0.y;
          acc[2] += w[k] * f1.x; acc[3] += w[k] * f1.y;
          acc[4] += w[k] * f2.x; acc[5] += w[k] * f2.y;
          acc[6] += w[k] * f3.x; acc[7] += w[k] * f3.y;
        }
    }
    wave_lds_fence();
  }

#pragma unroll
  for (int off = LPG; off < 64; off <<= 1) {
    lsum += __shfl_xor(lsum, off);
#pragma unroll
    for (int j = 0; j < 8; ++j) acc[j] += __shfl_xor(acc[j], off);
  }

  if (grp == 0 && act) {
    const float inv = 1.f / lsum;
    const float4 b0 = *(const float4*)(bias + lg * 8);
    const float4 b1 = *(const float4*)(bias + lg * 8 + 4);
    float4 o0, o1;
    o0.x = acc[0] * inv + b0.x; o0.y = acc[1] * inv + b0.y;
    o0.z = acc[2] * inv + b0.z; o0.w = acc[3] * inv + b0.w;
    o1.x = acc[4] * inv + b1.x; o1.y = acc[5] * inv + b1.y;
    o1.z = acc[6] * inv + b1.z; o1.w = acc[7] * inv + b1.w;
    if (RELU) {
      o0.x = fmaxf(o0.x, 0.f); o0.y = fmaxf(o0.y, 0.f);
      o0.z = fmaxf(o0.z, 0.f); o0.w = fmaxf(o0.w, 0.f);
      o1.x = fmaxf(o1.x, 0.f); o1.y = fmaxf(o1.y, 0.f);
      o1.z = fmaxf(o1.z, 0.f); o1.w = fmaxf(o1.w, 0.f);
    }
    *(float4*)(Out + (size_t)n * HC + lg * 8) = o0;
    *(float4*)(Out + (size_t)n * HC + lg * 8 + 4) = o1;
  }
}

// ======================= XCD-affine partial aggregation =======================
// Block bid -> XCD bid%8 (MI355X round-robin); XCD x owns src range x>>1.
// Each (node, range) pair produces an UNNORMALIZED partial sum (fp16) + per-head
// weight sum (fp32), written nontemporally. Gathers stay inside a 3.2 MB window
// per XCD -> L2-resident.
template <int H, int C, int HCP>
__global__ __launch_bounds__(256) void agg_part_kernel(const __half* __restrict__ Hbuf,
                                                       const float* __restrict__ als8,
                                                       const float* __restrict__ ald8,
                                                       const int* __restrict__ segptr,
                                                       const int* __restrict__ esrc,
                                                       __half* __restrict__ Ppart,
                                                       float* __restrict__ Plsum) {
  constexpr int HC = H * C;
  constexpr int NCHUNK = HC / 8;
  constexpr int GROUPS = 4;
  constexpr int LPG = 16;
  constexpr int UN = 3;
  constexpr int TPAD = 72;
  const int wave = threadIdx.x >> 6;
  const int lane = threadIdx.x & 63;
  const int grp = lane / LPG;
  const int lg = lane % LPG;
  const int xcd = blockIdx.x & 7;
  const int r = xcd >> 1;
  const int half = xcd & 1;
  const int nb = blockIdx.x >> 3;
  const int n = (nb * 2 + half) * 4 + wave;  // < 50000 by construction
  __shared__ float s_w[4][TPAD * H];
  __shared__ int s_src[4][TPAD];

  if (lane < TPAD - 64) s_src[wave][64 + lane] = 0;
  for (int z = lane; z < (TPAD - 64) * H; z += 64) s_w[wave][64 * H + z] = 0.f;

  const int e0 = segptr[n * RANGES + r];
  const int e1 = segptr[n * RANGES + r + 1];

  float aldn[H];
#pragma unroll
  for (int h = 0; h < H; ++h) aldn[h] = ald8[n * 8 + h];

  const int head = min((lg * 8) / C, H - 1);
  const bool act = lg < NCHUNK;

  float acc[8];
  float lsum = 0.f;
#pragma unroll
  for (int j = 0; j < 8; ++j) acc[j] = 0.f;

  for (int base = e0; base < e1; base += 64) {
    const int cnt = (e1 - base < 64) ? (e1 - base) : 64;
    int sreg = 0;
    if (lane < cnt) sreg = esrc[base + lane];
    s_src[wave][lane] = sreg;
    if (lane < cnt) {
      const float4 qa = *(const float4*)(als8 + (size_t)sreg * 8);
      const float4 qb = *(const float4*)(als8 + (size_t)sreg * 8 + 4);
      const float q[8] = {qa.x, qa.y, qa.z, qa.w, qb.x, qb.y, qb.z, qb.w};
#pragma unroll
      for (int h = 0; h < H; ++h) {
        float v = q[h] + aldn[h];
        v = v > 0.f ? v : 0.2f * v;
        s_w[wave][lane * H + h] = __expf(v);
      }
    } else {
#pragma unroll
      for (int h = 0; h < H; ++h) s_w[wave][lane * H + h] = 0.f;
    }
    wave_lds_fence();
    const int nit = (cnt + GROUPS - 1) / GROUPS;
    for (int i = 0; i < nit; i += UN) {
      int tt[UN], si[UN];
      uint4 v[UN];
      float w[UN];
#pragma unroll
      for (int k = 0; k < UN; ++k) tt[k] = (i + k) * GROUPS + grp;
#pragma unroll
      for (int k = 0; k < UN; ++k) si[k] = s_src[wave][tt[k]];
#pragma unroll
      for (int k = 0; k < UN; ++k)
        if (act) v[k] = *(const uint4*)(Hbuf + (size_t)si[k] * HCP + lg * 8);
#pragma unroll
      for (int k = 0; k < UN; ++k) w[k] = s_w[wave][tt[k] * H + head];
#pragma unroll
      for (int k = 0; k < UN; ++k)
        if (act) {
          const __half2* hp = (const __half2*)&v[k];
          float2 f0 = __half22float2(hp[0]);
          float2 f1 = __half22float2(hp[1]);
          float2 f2 = __half22float2(hp[2]);
          float2 f3 = __half22float2(hp[3]);
          lsum += w[k];
          acc[0] += w[k] * f0.x; acc[1] += w[k] * f0.y;
          acc[2] += w[k] * f1.x; acc[3] += w[k] * f1.y;
          acc[4] += w[k] * f2.x; acc[5] += w[k] * f2.y;
          acc[6] += w[k] * f3.x; acc[7] += w[k] * f3.y;
        }
    }
    wave_lds_fence();
  }

#pragma unroll
  for (int off = LPG; off < 64; off <<= 1) {
    lsum += __shfl_xor(lsum, off);
#pragma unroll
    for (int j = 0; j < 8; ++j) acc[j] += __shfl_xor(acc[j], off);
  }

  if (grp == 0 && act) {
    union { __half2 h2[4]; nvec4 u; } pk;
    pk.h2[0] = __floats2half2_rn(acc[0], acc[1]);
    pk.h2[1] = __floats2half2_rn(acc[2], acc[3]);
    pk.h2[2] = __floats2half2_rn(acc[4], acc[5]);
    pk.h2[3] = __floats2half2_rn(acc[6], acc[7]);
    __builtin_nontemporal_store(pk.u, (nvec4*)(Ppart + ((size_t)r * NNODES + n) * HC + lg * 8));
    if ((lg * 8) % C == 0)
      __builtin_nontemporal_store(lsum, Plsum + ((size_t)r * NNODES + n) * 8 + head);
  }
}

// combine: out[n] = (sum_r Ppart_r[n]) / (sum_r lsum_r[n]) + bias  (streaming)
template <int H, int C, int RELU>
__global__ __launch_bounds__(256) void combine_kernel(const __half* __restrict__ Ppart,
                                                      const float* __restrict__ Plsum,
                                                      const float* __restrict__ bias,
                                                      float* __restrict__ Out, int n_nodes) {
  constexpr int HC = H * C;
  constexpr int NCH = HC / 8;
  int t = blockIdx.x * 256 + threadIdx.x;
  if (t >= n_nodes * NCH) return;
  int n = t / NCH, ck = t % NCH;
  int head = (ck * 8) / C;
  float ls = 0.f;
  float a[8];
#pragma unroll
  for (int j = 0; j < 8; ++j) a[j] = 0.f;
#pragma unroll
  for (int r = 0; r < RANGES; ++r) {
    ls += Plsum[((size_t)r * NNODES + n) * 8 + head];
    uint4 u = *(const uint4*)(Ppart + ((size_t)r * NNODES + n) * HC + ck * 8);
    const __half2* hp = (const __half2*)&u;
#pragma unroll
    for (int p = 0; p < 4; ++p) {
      float2 f = __half22float2(hp[p]);
      a[2 * p] += f.x;
      a[2 * p + 1] += f.y;
    }
  }
  const float inv = 1.f / ls;
  const float4 b0 = *(const float4*)(bias + ck * 8);
  const float4 b1 = *(const float4*)(bias + ck * 8 + 4);
  float4 o0, o1;
  o0.x = a[0] * inv + b0.x; o0.y = a[1] * inv + b0.y;
  o0.z = a[2] * inv + b0.z; o0.w = a[3] * inv + b0.w;
  o1.x = a[4] * inv + b1.x; o1.y = a[5] * inv + b1.y;
  o1.z = a[6] * inv + b1.z; o1.w = a[7] * inv + b1.w;
  if (RELU) {
    o0.x = fmaxf(o0.x, 0.f); o0.y = fmaxf(o0.y, 0.f);
    o0.z = fmaxf(o0.z, 0.f); o0.w = fmaxf(o0.w, 0.f);
    o1.x = fmaxf(o1.x, 0.f); o1.y = fmaxf(o1.y, 0.f);
    o1.z = fmaxf(o1.z, 0.f); o1.w = fmaxf(o1.w, 0.f);
  }
  *(float4*)(Out + (size_t)n * HC + ck * 8) = o0;
  *(float4*)(Out + (size_t)n * HC + ck * 8 + 4) = o1;
}

// ---------------- launch ----------------
extern "C" void kernel_launch(void* const* d_in, const int* in_sizes, int n_in,
                              void* d_out, int out_size, void* d_ws, size_t ws_size,
                              hipStream_t stream) {
  const int N = NNODES;
  const float* x  = (const float*)d_in[0];
  const int* ei   = (const int*)d_in[1];
  const float* W1 = (const float*)d_in[2];
  const float* as1 = (const float*)d_in[3];
  const float* ad1 = (const float*)d_in[4];
  const float* b1  = (const float*)d_in[5];
  const float* W2  = (const float*)d_in[6];
  const float* as2 = (const float*)d_in[7];
  const float* ad2 = (const float*)d_in[8];
  const float* b2  = (const float*)d_in[9];
  const float* W3  = (const float*)d_in[10];
  const float* as3 = (const float*)d_in[11];
  const float* ad3 = (const float*)d_in[12];
  const float* b3  = (const float*)d_in[13];
  float* out = (float*)d_out;
  const int E = in_sizes[1] / 2;
  const int ET = E + N;
  const int NSEG = N * RANGES;  // 200000

  char* ws = (char*)d_ws;
  size_t off = 0;
  auto alloc = [&](size_t bytes) -> char* {
    char* p = ws + off;
    off += (bytes + 255) & ~(size_t)255;
    return p;
  };
  int* cnt     = (int*)alloc((size_t)NSEG * 4);
  int* cnt2    = (int*)alloc((size_t)NSEG * 4);
  int* incl0   = (int*)alloc((size_t)NSEG * 4);
  int* bs0     = (int*)alloc(1024 * 4);
  int* incl1   = (int*)alloc(1024 * 4);
  int* bs1     = (int*)alloc(256 * 4);
  int* incl2   = (int*)alloc(256 * 4);
  int* bs2     = (int*)alloc(256 * 4);
  int* segptr  = (int*)alloc((size_t)(NSEG + 1) * 4);
  int* esorted = (int*)alloc((size_t)ET * 4);
  float* als   = (float*)alloc((size_t)N * 8 * 4);
  float* ald   = (float*)alloc((size_t)N * 8 * 4);
  __half* hbuf = (__half*)alloc((size_t)N * 256 * 2);
  float* abuf  = (float*)alloc((size_t)N * 112 * 4);
  __half* ppart = (__half*)alloc((size_t)RANGES * N * 112 * 2);
  float* plsum  = (float*)alloc((size_t)RANGES * N * 8 * 4);
  const bool use_part = (off <= ws_size);

  hipMemsetAsync(cnt, 0, (size_t)NSEG * 4, stream);
  hipMemsetAsync(cnt2, 0, (size_t)NSEG * 4, stream);

  const int BSEG = (NSEG + 255) / 256;  // 782
  hist_kernel<<<(ET + 255) / 256, 256, 0, stream>>>(ei, E, N, cnt);
  scan1_kernel<<<BSEG, 256, 0, stream>>>(cnt, NSEG, incl0, bs0);
  scan1_kernel<<<(BSEG + 255) / 256, 256, 0, stream>>>(bs0, BSEG, incl1, bs1);
  scan1_kernel<<<1, 256, 0, stream>>>(bs1, (BSEG + 255) / 256, incl2, bs2);
  scan3seg_kernel<<<BSEG, 256, 0, stream>>>(incl0, incl1, incl2, NSEG, segptr);
  scatter_kernel<<<(ET + 255) / 256, 256, 0, stream>>>(ei, E, N, segptr, cnt2, esorted);

  // Layer 1: 128 -> 7x16, rows padded 112 -> 128 halves (3.2 MB per src range)
  gemm_kernel<128, 112, 128, 128><<<N / 16, 128, 0, stream>>>(x, W1, hbuf);
  alpha_kernel<7, 16, 128><<<(N * 7 + 255) / 256, 256, 0, stream>>>(hbuf, as1, ad1, als, ald, N);
  if (use_part) {
    agg_part_kernel<7, 16, 128><<<(N / 8) * 8, 256, 0, stream>>>(hbuf, als, ald, segptr, esorted, ppart, plsum);
    combine_kernel<7, 16, 1><<<(N * 14 + 255) / 256, 256, 0, stream>>>(ppart, plsum, b1, abuf, N);
  } else {
    agg_kernel<7, 16, 128, 1><<<(N + 3) / 4, 256, 0, stream>>>(hbuf, als, ald, segptr, esorted, b1, abuf, N);
  }
  // Layer 2: 112 -> 6x16, stride 96 halves (2.4 MB per src range)
  gemm_kernel<112, 96, 96, 128><<<N / 16, 128, 0, stream>>>(abuf, W2, hbuf);
  alpha_kernel<6, 16, 96><<<(N * 6 + 255) / 256, 256, 0, stream>>>(hbuf, as2, ad2, als, ald, N);
  if (use_part) {
    agg_part_kernel<6, 16, 96><<<(N / 8) * 8, 256, 0, stream>>>(hbuf, als, ald, segptr, esorted, ppart, plsum);
    combine_kernel<6, 16, 1><<<(N * 12 + 255) / 256, 256, 0, stream>>>(ppart, plsum, b2, abuf, N);
  } else {
    agg_kernel<6, 16, 96, 1><<<(N + 3) / 4, 256, 0, stream>>>(hbuf, als, ald, segptr, esorted, b2, abuf, N);
  }
  // Layer 3: 96 -> 6x40 (no relu), rows padded 240 -> 256 halves; range 6.4 MB > L2 -> plain
  gemm_kernel<96, 240, 256, 256><<<N / 16, 256, 0, stream>>>(abuf, W3, hbuf);
  alpha_kernel<6, 40, 256><<<(N * 6 + 255) / 256, 256, 0, stream>>>(hbuf, as3, ad3, als, ald, N);
  agg_kernel<6, 40, 256, 0><<<(N + 3) / 4, 256, 0, stream>>>(hbuf, als, ald, segptr, esorted, b3, out, N);
}

// Round 5
// 497.919 us; speedup vs baseline: 1.2175x; 1.2175x over previous
//
#include <hip/hip_runtime.h>
#include <hip/hip_fp16.h>
#include <cstdint>

#define NNODES 50000
#define RANGES 4
#define RSPAN 12500  // NNODES / RANGES

typedef unsigned int nvec4 __attribute__((ext_vector_type(4)));  // native vec for nontemporal builtins

__device__ inline void wave_lds_fence() {
  asm volatile("s_waitcnt lgkmcnt(0)" ::: "memory");
  __builtin_amdgcn_wave_barrier();
}

// ---------------- segmented CSR build: segment = dst*RANGES + src/RSPAN ----------------
__global__ void hist_kernel(const int* __restrict__ ei, int E, int Nn, int* __restrict__ cnt) {
  int i = blockIdx.x * blockDim.x + threadIdx.x;
  int ET = E + Nn;
  if (i >= ET) return;
  int s, d;
  if (i < E) { s = ei[i]; d = ei[E + i]; }
  else       { s = i - E; d = i - E; }
  atomicAdd(&cnt[d * RANGES + s / RSPAN], 1);
}

__global__ void scan1_kernel(const int* __restrict__ in, int n, int* __restrict__ incl,
                             int* __restrict__ bsum) {
  __shared__ int sd[256];
  int g = blockIdx.x * 256 + threadIdx.x;
  int v = (g < n) ? in[g] : 0;
  sd[threadIdx.x] = v;
  __syncthreads();
  for (int off = 1; off < 256; off <<= 1) {
    int t = (threadIdx.x >= off) ? sd[threadIdx.x - off] : 0;
    __syncthreads();
    sd[threadIdx.x] += t;
    __syncthreads();
  }
  if (g < n) incl[g] = sd[threadIdx.x];
  if (threadIdx.x == 255) bsum[blockIdx.x] = sd[255];
}

// segptr[g+1] = incl0[g] + global-exclusive-prefix(block b0) using two scan levels
__global__ void scan3seg_kernel(const int* __restrict__ incl0, const int* __restrict__ incl1,
                                const int* __restrict__ incl2, int n, int* __restrict__ segptr) {
  int g = blockIdx.x * 256 + threadIdx.x;
  if (g == 0) segptr[0] = 0;
  if (g < n) {
    int b0 = g >> 8;
    int off = 0;
    if (b0 > 0) {
      int i = b0 - 1;
      off = incl1[i];
      int j = i >> 8;
      if (j > 0) off += incl2[j - 1];
    }
    segptr[g + 1] = incl0[g] + off;
  }
}

__global__ void scatter_kernel(const int* __restrict__ ei, int E, int Nn,
                               const int* __restrict__ segptr, int* __restrict__ cnt2,
                               int* __restrict__ esorted) {
  int i = blockIdx.x * blockDim.x + threadIdx.x;
  int ET = E + Nn;
  if (i >= ET) return;
  int s, d;
  if (i < E) { s = ei[i]; d = ei[E + i]; }
  else       { s = i - E; d = i - E; }
  int seg = d * RANGES + s / RSPAN;
  int pos = segptr[seg] + atomicAdd(&cnt2[seg], 1);
  esorted[pos] = s;
}

// ---------------- GEMM: Hout[N,HCP](fp16, row stride HCP) = X[N,FIN](fp32) @ W[FIN,HC] ------
template <int FIN, int HC, int HCP, int BLOCK>
__global__ __launch_bounds__(BLOCK) void gemm_kernel(const float* __restrict__ X,
                                                     const float* __restrict__ W,
                                                     __half* __restrict__ Hout) {
  constexpr int NT = 16;
  constexpr int TM = 4, TN = 4;
  constexpr int CG = HC / TN;
  __shared__ __align__(16) float xs[FIN * NT];  // [k][node]
  const int n0 = blockIdx.x * NT;
  for (int i = threadIdx.x * 4; i < NT * FIN; i += BLOCK * 4) {
    float4 v = *(const float4*)(X + (size_t)n0 * FIN + i);
    int node = i / FIN, k = i % FIN;
    xs[(k + 0) * NT + node] = v.x;
    xs[(k + 1) * NT + node] = v.y;
    xs[(k + 2) * NT + node] = v.z;
    xs[(k + 3) * NT + node] = v.w;
  }
  __syncthreads();
  const int cg = threadIdx.x % CG;
  const int ng = threadIdx.x / CG;
  if (ng >= NT / TM) return;
  const int c0 = cg * TN;
  const int i0 = ng * TM;
  float acc[TM][TN];
#pragma unroll
  for (int i = 0; i < TM; ++i)
#pragma unroll
    for (int j = 0; j < TN; ++j) acc[i][j] = 0.f;
#pragma unroll 4
  for (int k = 0; k < FIN; ++k) {
    const float4 wv = *(const float4*)(W + (size_t)k * HC + c0);
    const float4 xv = *(const float4*)(xs + k * NT + i0);
    acc[0][0] += xv.x * wv.x; acc[0][1] += xv.x * wv.y; acc[0][2] += xv.x * wv.z; acc[0][3] += xv.x * wv.w;
    acc[1][0] += xv.y * wv.x; acc[1][1] += xv.y * wv.y; acc[1][2] += xv.y * wv.z; acc[1][3] += xv.y * wv.w;
    acc[2][0] += xv.z * wv.x; acc[2][1] += xv.z * wv.y; acc[2][2] += xv.z * wv.z; acc[2][3] += xv.z * wv.w;
    acc[3][0] += xv.w * wv.x; acc[3][1] += xv.w * wv.y; acc[3][2] += xv.w * wv.z; acc[3][3] += xv.w * wv.w;
  }
#pragma unroll
  for (int i = 0; i < TM; ++i) {
    union { __half2 h2[2]; uint2 u; } pk;
    pk.h2[0] = __floats2half2_rn(acc[i][0], acc[i][1]);
    pk.h2[1] = __floats2half2_rn(acc[i][2], acc[i][3]);
    *(uint2*)(Hout + (size_t)(n0 + i0 + i) * HCP + c0) = pk.u;
  }
}

// ---------------- attention logits ----------------
template <int H, int C, int HCP>
__global__ void alpha_kernel(const __half* __restrict__ Hbuf, const float* __restrict__ a_s,
                             const float* __restrict__ a_d, float* __restrict__ als8,
                             float* __restrict__ ald8, int n_nodes) {
  int i = blockIdx.x * blockDim.x + threadIdx.x;
  if (i >= n_nodes * H) return;
  int n = i / H, h = i % H;
  const __half2* hp = (const __half2*)(Hbuf + (size_t)n * HCP + (size_t)h * C);
  float s1 = 0.f, s2 = 0.f;
#pragma unroll
  for (int c = 0; c < C / 2; ++c) {
    float2 f = __half22float2(hp[c]);
    s1 += f.x * a_s[h * C + 2 * c] + f.y * a_s[h * C + 2 * c + 1];
    s2 += f.x * a_d[h * C + 2 * c] + f.y * a_d[h * C + 2 * c + 1];
  }
  als8[n * 8 + h] = s1;
  ald8[n * 8 + h] = s2;
}

// ======================= full-row segment softmax + aggregate (plain path) ==================
// Used for layer 3 (range footprint too big for L2) and as ws_size fallback.
// Row = 4 contiguous segments [segptr[n*4], segptr[n*4+4]).
template <int H, int C, int HCP, int RELU>
__global__ __launch_bounds__(256) void agg_kernel(const __half* __restrict__ Hbuf,
                                                  const float* __restrict__ als8,
                                                  const float* __restrict__ ald8,
                                                  const int* __restrict__ segptr,
                                                  const int* __restrict__ esrc,
                                                  const float* __restrict__ bias,
                                                  float* __restrict__ Out, int n_nodes) {
  constexpr int HC = H * C;
  constexpr int NCHUNK = HC / 8;
  constexpr int GROUPS = (NCHUNK <= 16) ? 4 : 2;
  constexpr int LPG = 64 / GROUPS;
  constexpr int UN = 3;
  constexpr int TPAD = 72;
  const int wave = threadIdx.x >> 6;
  const int lane = threadIdx.x & 63;
  const int grp = lane / LPG;
  const int lg = lane % LPG;
  const int n = blockIdx.x * 4 + wave;
  __shared__ float s_w[4][TPAD * H];
  __shared__ int s_src[4][TPAD];
  if (n >= n_nodes) return;

  if (lane < TPAD - 64) s_src[wave][64 + lane] = 0;
  for (int z = lane; z < (TPAD - 64) * H; z += 64) s_w[wave][64 * H + z] = 0.f;

  const int e0 = segptr[n * RANGES];
  const int e1 = segptr[n * RANGES + RANGES];

  float aldn[H];
#pragma unroll
  for (int h = 0; h < H; ++h) aldn[h] = ald8[n * 8 + h];

  const int head = min((lg * 8) / C, H - 1);
  const bool act = lg < NCHUNK;

  float acc[8];
  float lsum = 0.f;
#pragma unroll
  for (int j = 0; j < 8; ++j) acc[j] = 0.f;

  for (int base = e0; base < e1; base += 64) {
    const int cnt = (e1 - base < 64) ? (e1 - base) : 64;
    int sreg = 0;
    if (lane < cnt) sreg = esrc[base + lane];
    s_src[wave][lane] = sreg;
    if (lane < cnt) {
      const float4 qa = *(const float4*)(als8 + (size_t)sreg * 8);
      const float4 qb = *(const float4*)(als8 + (size_t)sreg * 8 + 4);
      const float q[8] = {qa.x, qa.y, qa.z, qa.w, qb.x, qb.y, qb.z, qb.w};
#pragma unroll
      for (int h = 0; h < H; ++h) {
        float v = q[h] + aldn[h];
        v = v > 0.f ? v : 0.2f * v;
        s_w[wave][lane * H + h] = __expf(v);
      }
    } else {
#pragma unroll
      for (int h = 0; h < H; ++h) s_w[wave][lane * H + h] = 0.f;
    }
    wave_lds_fence();
    const int nit = (cnt + GROUPS - 1) / GROUPS;
    for (int i = 0; i < nit; i += UN) {
      int tt[UN], si[UN];
      uint4 v[UN];
      float w[UN];
#pragma unroll
      for (int k = 0; k < UN; ++k) tt[k] = (i + k) * GROUPS + grp;
#pragma unroll
      for (int k = 0; k < UN; ++k) si[k] = s_src[wave][tt[k]];
#pragma unroll
      for (int k = 0; k < UN; ++k)
        if (act) v[k] = *(const uint4*)(Hbuf + (size_t)si[k] * HCP + lg * 8);
#pragma unroll
      for (int k = 0; k < UN; ++k) w[k] = s_w[wave][tt[k] * H + head];
#pragma unroll
      for (int k = 0; k < UN; ++k)
        if (act) {
          const __half2* hp = (const __half2*)&v[k];
          float2 f0 = __half22float2(hp[0]);
          float2 f1 = __half22float2(hp[1]);
          float2 f2 = __half22float2(hp[2]);
          float2 f3 = __half22float2(hp[3]);
          lsum += w[k];
          acc[0] += w[k] * f0.x; acc[1] += w[k] * f0.y;
          acc[2] += w[k] * f1.x; acc[3] += w[k] * f1.y;
          acc[4] += w[k] * f2.x; acc[5] += w[k] * f2.y;
          acc[6] += w[k] * f3.x; acc[7] += w[k] * f3.y;
        }
    }
    wave_lds_fence();
  }

#pragma unroll
  for (int off = LPG; off < 64; off <<= 1) {
    lsum += __shfl_xor(lsum, off);
#pragma unroll
    for (int j = 0; j < 8; ++j) acc[j] += __shfl_xor(acc[j], off);
  }

  if (grp == 0 && act) {
    const float inv = 1.f / lsum;
    const float4 b0 = *(const float4*)(bias + lg * 8);
    const float4 b1 = *(const float4*)(bias + lg * 8 + 4);
    float4 o0, o1;
    o0.x = acc[0] * inv + b0.x; o0.y = acc[1] * inv + b0.y;
    o0.z = acc[2] * inv + b0.z; o0.w = acc[3] * inv + b0.w;
    o1.x = acc[4] * inv + b1.x; o1.y = acc[5] * inv + b1.y;
    o1.z = acc[6] * inv + b1.z; o1.w = acc[7] * inv + b1.w;
    if (RELU) {
      o0.x = fmaxf(o0.x, 0.f); o0.y = fmaxf(o0.y, 0.f);
      o0.z = fmaxf(o0.z, 0.f); o0.w = fmaxf(o0.w, 0.f);
      o1.x = fmaxf(o1.x, 0.f); o1.y = fmaxf(o1.y, 0.f);
      o1.z = fmaxf(o1.z, 0.f); o1.w = fmaxf(o1.w, 0.f);
    }
    *(float4*)(Out + (size_t)n * HC + lg * 8) = o0;
    *(float4*)(Out + (size_t)n * HC + lg * 8 + 4) = o1;
  }
}

// ======================= XCD-affine partial aggregation (lean, group-per-task) ==============
// Block bid -> XCD bid&7; XCD x owns src range x>>1 -> gathers stay in a 3.2 MB L2 window.
// Each 16-lane group owns ONE (node, range) segment entirely: serial edge loop of exactly
// cnt iterations, softmax weight computed inline (als8/ald8 gathers are L2-hits), no LDS,
// no fences, no cross-group reduction. Next edge's (src, als) prefetched each iteration.
template <int H, int C, int HCP>
__global__ __launch_bounds__(256) void agg_part_kernel(const __half* __restrict__ Hbuf,
                                                       const float* __restrict__ als8,
                                                       const float* __restrict__ ald8,
                                                       const int* __restrict__ segptr,
                                                       const int* __restrict__ esrc,
                                                       __half* __restrict__ Ppart,
                                                       float* __restrict__ Plsum, int n_nodes) {
  constexpr int HC = H * C;
  constexpr int NCHUNK = HC / 8;   // 14 (L1) or 12 (L2)
  constexpr int CPH = C / 8;       // chunks per head (2 for C=16)
  const int lane = threadIdx.x & 63;
  const int wave = threadIdx.x >> 6;
  const int grp = lane >> 4;
  const int lg = lane & 15;
  const int xcd = blockIdx.x & 7;
  const int r = xcd >> 1;
  const int half = xcd & 1;
  const int nb = blockIdx.x >> 3;
  const int n = (nb * 2 + half) * 16 + wave * 4 + grp;
  if (n >= n_nodes) return;

  const int head = lg / CPH;  // may be >= H on inactive lanes; als8/ald8 stride-8 pad keeps it in-bounds
  const bool act = lg < NCHUNK;
  const float aldh = ald8[(size_t)n * 8 + head];

  const int e0 = segptr[n * RANGES + r];
  const int e1 = segptr[n * RANGES + r + 1];

  float acc[8];
  float lsum = 0.f;
#pragma unroll
  for (int j = 0; j < 8; ++j) acc[j] = 0.f;

  int sreg = (e0 < e1) ? esrc[e0] : 0;
  float av = (e0 < e1) ? als8[(size_t)sreg * 8 + head] : 0.f;
  for (int t = e0; t < e1; ++t) {
    uint4 v;
    if (act) v = *(const uint4*)(Hbuf + (size_t)sreg * HCP + lg * 8);
    // prefetch next edge's src + als while the gather is in flight
    int nsreg = (t + 1 < e1) ? esrc[t + 1] : 0;
    float nav = (t + 1 < e1) ? als8[(size_t)nsreg * 8 + head] : 0.f;
    float e = av + aldh;
    e = e > 0.f ? e : 0.2f * e;  // leaky_relu 0.2
    float w = __expf(e);
    if (act) {
      const __half2* hp = (const __half2*)&v;
      float2 f0 = __half22float2(hp[0]);
      float2 f1 = __half22float2(hp[1]);
      float2 f2 = __half22float2(hp[2]);
      float2 f3 = __half22float2(hp[3]);
      lsum += w;
      acc[0] += w * f0.x; acc[1] += w * f0.y;
      acc[2] += w * f1.x; acc[3] += w * f1.y;
      acc[4] += w * f2.x; acc[5] += w * f2.y;
      acc[6] += w * f3.x; acc[7] += w * f3.y;
    }
    sreg = nsreg;
    av = nav;
  }

  if (act) {
    union { __half2 h2[4]; nvec4 u; } pk;
    pk.h2[0] = __floats2half2_rn(acc[0], acc[1]);
    pk.h2[1] = __floats2half2_rn(acc[2], acc[3]);
    pk.h2[2] = __floats2half2_rn(acc[4], acc[5]);
    pk.h2[3] = __floats2half2_rn(acc[6], acc[7]);
    __builtin_nontemporal_store(pk.u, (nvec4*)(Ppart + ((size_t)r * NNODES + n) * HC + lg * 8));
    if ((lg % CPH) == 0)
      __builtin_nontemporal_store(lsum, Plsum + ((size_t)r * NNODES + n) * 8 + head);
  }
}

// combine: out[n] = (sum_r Ppart_r[n]) / (sum_r lsum_r[n]) + bias  (streaming)
template <int H, int C, int RELU>
__global__ __launch_bounds__(256) void combine_kernel(const __half* __restrict__ Ppart,
                                                      const float* __restrict__ Plsum,
                                                      const float* __restrict__ bias,
                                                      float* __restrict__ Out, int n_nodes) {
  constexpr int HC = H * C;
  constexpr int NCH = HC / 8;
  int t = blockIdx.x * 256 + threadIdx.x;
  if (t >= n_nodes * NCH) return;
  int n = t / NCH, ck = t % NCH;
  int head = (ck * 8) / C;
  float ls = 0.f;
  float a[8];
#pragma unroll
  for (int j = 0; j < 8; ++j) a[j] = 0.f;
#pragma unroll
  for (int r = 0; r < RANGES; ++r) {
    ls += Plsum[((size_t)r * NNODES + n) * 8 + head];
    uint4 u = *(const uint4*)(Ppart + ((size_t)r * NNODES + n) * HC + ck * 8);
    const __half2* hp = (const __half2*)&u;
#pragma unroll
    for (int p = 0; p < 4; ++p) {
      float2 f = __half22float2(hp[p]);
      a[2 * p] += f.x;
      a[2 * p + 1] += f.y;
    }
  }
  const float inv = 1.f / ls;
  const float4 b0 = *(const float4*)(bias + ck * 8);
  const float4 b1 = *(const float4*)(bias + ck * 8 + 4);
  float4 o0, o1;
  o0.x = a[0] * inv + b0.x; o0.y = a[1] * inv + b0.y;
  o0.z = a[2] * inv + b0.z; o0.w = a[3] * inv + b0.w;
  o1.x = a[4] * inv + b1.x; o1.y = a[5] * inv + b1.y;
  o1.z = a[6] * inv + b1.z; o1.w = a[7] * inv + b1.w;
  if (RELU) {
    o0.x = fmaxf(o0.x, 0.f); o0.y = fmaxf(o0.y, 0.f);
    o0.z = fmaxf(o0.z, 0.f); o0.w = fmaxf(o0.w, 0.f);
    o1.x = fmaxf(o1.x, 0.f); o1.y = fmaxf(o1.y, 0.f);
    o1.z = fmaxf(o1.z, 0.f); o1.w = fmaxf(o1.w, 0.f);
  }
  *(float4*)(Out + (size_t)n * HC + ck * 8) = o0;
  *(float4*)(Out + (size_t)n * HC + ck * 8 + 4) = o1;
}

// ---------------- launch ----------------
extern "C" void kernel_launch(void* const* d_in, const int* in_sizes, int n_in,
                              void* d_out, int out_size, void* d_ws, size_t ws_size,
                              hipStream_t stream) {
  const int N = NNODES;
  const float* x  = (const float*)d_in[0];
  const int* ei   = (const int*)d_in[1];
  const float* W1 = (const float*)d_in[2];
  const float* as1 = (const float*)d_in[3];
  const float* ad1 = (const float*)d_in[4];
  const float* b1  = (const float*)d_in[5];
  const float* W2  = (const float*)d_in[6];
  const float* as2 = (const float*)d_in[7];
  const float* ad2 = (const float*)d_in[8];
  const float* b2  = (const float*)d_in[9];
  const float* W3  = (const float*)d_in[10];
  const float* as3 = (const float*)d_in[11];
  const float* ad3 = (const float*)d_in[12];
  const float* b3  = (const float*)d_in[13];
  float* out = (float*)d_out;
  const int E = in_sizes[1] / 2;
  const int ET = E + N;
  const int NSEG = N * RANGES;  // 200000

  char* ws = (char*)d_ws;
  size_t off = 0;
  auto alloc = [&](size_t bytes) -> char* {
    char* p = ws + off;
    off += (bytes + 255) & ~(size_t)255;
    return p;
  };
  int* cnt     = (int*)alloc((size_t)NSEG * 4);
  int* cnt2    = (int*)alloc((size_t)NSEG * 4);
  int* incl0   = (int*)alloc((size_t)NSEG * 4);
  int* bs0     = (int*)alloc(1024 * 4);
  int* incl1   = (int*)alloc(1024 * 4);
  int* bs1     = (int*)alloc(256 * 4);
  int* incl2   = (int*)alloc(256 * 4);
  int* bs2     = (int*)alloc(256 * 4);
  int* segptr  = (int*)alloc((size_t)(NSEG + 1) * 4);
  int* esorted = (int*)alloc((size_t)ET * 4);
  float* als   = (float*)alloc((size_t)N * 8 * 4);
  float* ald   = (float*)alloc((size_t)N * 8 * 4);
  __half* hbuf = (__half*)alloc((size_t)N * 256 * 2);
  float* abuf  = (float*)alloc((size_t)N * 112 * 4);
  __half* ppart = (__half*)alloc((size_t)RANGES * N * 112 * 2);
  float* plsum  = (float*)alloc((size_t)RANGES * N * 8 * 4);
  const bool use_part = (off <= ws_size);

  hipMemsetAsync(cnt, 0, (size_t)NSEG * 4, stream);
  hipMemsetAsync(cnt2, 0, (size_t)NSEG * 4, stream);

  const int BSEG = (NSEG + 255) / 256;  // 782
  hist_kernel<<<(ET + 255) / 256, 256, 0, stream>>>(ei, E, N, cnt);
  scan1_kernel<<<BSEG, 256, 0, stream>>>(cnt, NSEG, incl0, bs0);
  scan1_kernel<<<(BSEG + 255) / 256, 256, 0, stream>>>(bs0, BSEG, incl1, bs1);
  scan1_kernel<<<1, 256, 0, stream>>>(bs1, (BSEG + 255) / 256, incl2, bs2);
  scan3seg_kernel<<<BSEG, 256, 0, stream>>>(incl0, incl1, incl2, NSEG, segptr);
  scatter_kernel<<<(ET + 255) / 256, 256, 0, stream>>>(ei, E, N, segptr, cnt2, esorted);

  // partial-agg grid: 16 nodes x 1 range per block; 8 blocks cover 32 nodes x all 4 ranges
  const int GPART = ((N + 31) / 32) * 8;  // 12504 blocks

  // Layer 1: 128 -> 7x16, rows padded 112 -> 128 halves (3.2 MB per src range)
  gemm_kernel<128, 112, 128, 128><<<N / 16, 128, 0, stream>>>(x, W1, hbuf);
  alpha_kernel<7, 16, 128><<<(N * 7 + 255) / 256, 256, 0, stream>>>(hbuf, as1, ad1, als, ald, N);
  if (use_part) {
    agg_part_kernel<7, 16, 128><<<GPART, 256, 0, stream>>>(hbuf, als, ald, segptr, esorted, ppart, plsum, N);
    combine_kernel<7, 16, 1><<<(N * 14 + 255) / 256, 256, 0, stream>>>(ppart, plsum, b1, abuf, N);
  } else {
    agg_kernel<7, 16, 128, 1><<<(N + 3) / 4, 256, 0, stream>>>(hbuf, als, ald, segptr, esorted, b1, abuf, N);
  }
  // Layer 2: 112 -> 6x16, stride 96 halves (2.4 MB per src range)
  gemm_kernel<112, 96, 96, 128><<<N / 16, 128, 0, stream>>>(abuf, W2, hbuf);
  alpha_kernel<6, 16, 96><<<(N * 6 + 255) / 256, 256, 0, stream>>>(hbuf, as2, ad2, als, ald, N);
  if (use_part) {
    agg_part_kernel<6, 16, 96><<<GPART, 256, 0, stream>>>(hbuf, als, ald, segptr, esorted, ppart, plsum, N);
    combine_kernel<6, 16, 1><<<(N * 12 + 255) / 256, 256, 0, stream>>>(ppart, plsum, b2, abuf, N);
  } else {
    agg_kernel<6, 16, 96, 1><<<(N + 3) / 4, 256, 0, stream>>>(hbuf, als, ald, segptr, esorted, b2, abuf, N);
  }
  // Layer 3: 96 -> 6x40 (no relu), rows padded 240 -> 256 halves; range 6.4 MB > L2 -> plain
  gemm_kernel<96, 240, 256, 256><<<N / 16, 256, 0, stream>>>(abuf, W3, hbuf);
  alpha_kernel<6, 40, 256><<<(N * 6 + 255) / 256, 256, 0, stream>>>(hbuf, as3, ad3, als, ald, N);
  agg_kernel<6, 40, 256, 0><<<(N + 3) / 4, 256, 0, stream>>>(hbuf, als, ald, segptr, esorted, b3, out, N);
}